// Round 15
// baseline (75.986 us; speedup 1.0000x reference)
//
#include <hip/hip_runtime.h>
#include <hip/hip_bf16.h>

// ---------- helpers ----------
typedef __attribute__((ext_vector_type(4))) float f32x4;
typedef __attribute__((ext_vector_type(8))) short s16x8;

#define MFMA16(a, b, c) __builtin_amdgcn_mfma_f32_16x16x32_bf16(a, b, c, 0, 0, 0)

__device__ __forceinline__ void gld_lds16(const void* g, void* l) {
  __builtin_amdgcn_global_load_lds(
      (const __attribute__((address_space(1))) unsigned int*)g,
      (__attribute__((address_space(3))) unsigned int*)l, 16, 0, 0);
}

__device__ __forceinline__ unsigned short f2bf(float f) {
  union { __hip_bfloat16 b; unsigned short u; } cv;
  cv.b = __float2bfloat16(f);
  return cv.u;
}
__device__ __forceinline__ float bf2f(unsigned short u) {
  union { unsigned short u; __hip_bfloat16 b; } cv;
  cv.u = u;
  return __bfloat162float(cv.b);
}

// ---------- kernel 1: merged prepass ----------
__global__ void prep(const float* Xq, unsigned short* xq,
                     const float* Xk, unsigned short* xk,
                     const float* Xv, unsigned short* xv,
                     const float* W0, unsigned short* H0,
                     const float* W1, unsigned short* H1,
                     const float* W2, unsigned short* H2,
                     const float* W3, unsigned short* H3) {
  __shared__ float tile[64 * 65];
  const int bid = blockIdx.x;
  const int t = threadIdx.x;
  if (bid < 12288) {
    const float* src; unsigned short* h;
    const int which = bid / 4096;
    if (which == 0) { src = Xq; h = xq; }
    else if (which == 1) { src = Xk; h = xk; }
    else { src = Xv; h = xv; }
    const int i = (bid - which * 4096) * 256 + t;   // float4 unit
    float4 v = ((const float4*)src)[i];
    ((ushort4*)h)[i] = make_ushort4(f2bf(v.x), f2bf(v.y), f2bf(v.z), f2bf(v.w));
  } else {
    const int bid2 = bid - 12288;
    const float* W; unsigned short* H;
    switch (bid2 >> 8) {
      case 0: W = W0; H = H0; break;
      case 1: W = W1; H = H1; break;
      case 2: W = W2; H = H2; break;
      default: W = W3; H = H3; break;
    }
    const int tx = bid2 & 255;
    const int tk0 = (tx & 15) * 64;   // k tile
    const int tn0 = (tx >> 4) * 64;   // n tile
    for (int i = 0; i < 16; ++i) {
      int idx = i * 256 + t;
      int r = idx >> 6, c = idx & 63;
      tile[r * 65 + c] = W[(size_t)(tk0 + r) * 1024 + tn0 + c];
    }
    __syncthreads();
    for (int i = 0; i < 16; ++i) {
      int idx = i * 256 + t;
      int r = idx >> 6, c = idx & 63;   // r: n offset, c: k offset
      H[(size_t)(tn0 + r) * 1024 + tk0 + c] = f2bf(tile[c * 65 + r]);
    }
  }
}

// ---------- LDS layout (BK=64, bf16) ----------
// Row = 64 shorts = one 128-B LDS row. Granule gno of row r at slot
// gno^(r&7); gno -> k offset (gno>>2)*32 + (gno&3)*8.
// Read frag (row ar, k-group ks, lane gh): slot = ((ks<<2)|gh) ^ (ar&7).

// ---------- kernel 3a: QKV bf16 GEMM, 128x64 tile, 4 waves, BK=64, dbuf ----------
// 1536 blocks (3 gemms x 512), 48 KB LDS -> ~3 blocks/CU resident: cross-block
// overlap fills barrier drains (best measured GEMM rate this session: R14 oproj).
// g==0,1 (Q,K): out [b*16+h][s][64]. g==2 (V): out TRANSPOSED [b*16+h][d][2048 s].
struct QkvArgs {
  const unsigned short* A[3];
  const unsigned short* B[3];
  const float* bias[3];
  unsigned short* out[3];
};

__global__ __launch_bounds__(256, 3)
void gemm_qkv(QkvArgs args) {
  const int K = 1024;
  __shared__ __align__(16) unsigned short lds[24576];   // A 2x16KB | B 2x8KB
  const int tid = threadIdx.x;
  const int lane = tid & 63, wid = tid >> 6;

  // XCD-aware bijective swizzle (1536 % 8 == 0)
  const int nwg = 1536;
  const int orig = blockIdx.x;
  const int swz = (orig & 7) * (nwg >> 3) + (orig >> 3);
  const int g = swz >> 9;            // 512 blocks per gemm (32 M x 16 N)
  const int tl = swz & 511;
  const int m0 = (tl >> 4) * 128, n0 = (tl & 15) * 64;

  const unsigned short* A = args.A[g];
  const unsigned short* B = args.B[g];
  const float* bias = args.bias[g];
  unsigned short* out = args.out[g];

  const int wm = (wid >> 1) * 64, wn = (wid & 1) * 32;   // wave tile 64x32
  const int fr = lane & 15, gh = lane >> 4;

  // A: 128 rows -> 4 sweeps; B: 64 rows -> 2 sweeps
  const unsigned short* aP[4]; int aDst[4];
  #pragma unroll
  for (int s = 0; s < 4; ++s) {
    const int G = s * 256 + tid;
    const int r = G >> 3, slot = G & 7;
    const int gno = slot ^ (r & 7);
    const int ko = (gno >> 2) * 32 + (gno & 3) * 8;
    aP[s] = A + (size_t)(m0 + r) * K + ko;
    aDst[s] = G * 8;
  }
  const unsigned short* bP[2]; int bDst[2];
  #pragma unroll
  for (int s = 0; s < 2; ++s) {
    const int G = s * 256 + tid;
    const int r = G >> 3, slot = G & 7;
    const int gno = slot ^ (r & 7);
    const int ko = (gno >> 2) * 32 + (gno & 3) * 8;
    bP[s] = B + (size_t)(n0 + r) * K + ko;
    bDst[s] = G * 8;
  }
  auto stageAll = [&](int u, int kt) {
    #pragma unroll
    for (int s = 0; s < 4; ++s)
      gld_lds16(aP[s] + kt, &lds[u * 8192 + aDst[s]]);
    #pragma unroll
    for (int s = 0; s < 2; ++s)
      gld_lds16(bP[s] + kt, &lds[16384 + u * 4096 + bDst[s]]);
  };

  f32x4 acc[4][2] = {};

  stageAll(0, 0);
  asm volatile("s_waitcnt vmcnt(0)" ::: "memory");
  __builtin_amdgcn_s_barrier();
  __builtin_amdgcn_sched_barrier(0);

  #pragma unroll 1
  for (int t = 0; t < 16; ++t) {
    const int u = t & 1;
    if (t < 15) stageAll(u ^ 1, (t + 1) * 64);
    const unsigned short* La = &lds[u * 8192];
    const unsigned short* Lb = &lds[16384 + u * 4096];
    s16x8 b[2][2];
    #pragma unroll
    for (int ks = 0; ks < 2; ++ks)
      #pragma unroll
      for (int nt = 0; nt < 2; ++nt) {
        const int br = wn + nt * 16 + fr;
        b[ks][nt] = *(const s16x8*)&Lb[br * 64 + (((ks << 2) | gh) ^ (br & 7)) * 8];
      }
    #pragma unroll
    for (int q = 0; q < 2; ++q) {
      s16x8 a[2][2];
      #pragma unroll
      for (int i = 0; i < 2; ++i)
        #pragma unroll
        for (int ks = 0; ks < 2; ++ks) {
          const int ar = wm + (q * 2 + i) * 16 + fr;
          a[i][ks] = *(const s16x8*)&La[ar * 64 + (((ks << 2) | gh) ^ (ar & 7)) * 8];
        }
      #pragma unroll
      for (int i = 0; i < 2; ++i)
        #pragma unroll
        for (int nt = 0; nt < 2; ++nt) {
          acc[q * 2 + i][nt] = MFMA16(a[i][0], b[0][nt], acc[q * 2 + i][nt]);
          acc[q * 2 + i][nt] = MFMA16(a[i][1], b[1][nt], acc[q * 2 + i][nt]);
        }
    }
    __builtin_amdgcn_sched_barrier(0);
    if (t < 15) { asm volatile("s_waitcnt vmcnt(0)" ::: "memory"); }
    __builtin_amdgcn_s_barrier();
    __builtin_amdgcn_sched_barrier(0);
  }

  // ---- epilogue via LDS transpose (N-tile == one head: h = n0>>6)
  float bv[2];
  #pragma unroll
  for (int nt = 0; nt < 2; ++nt) bv[nt] = bias[n0 + wn + nt * 16 + fr];
  unsigned short* eb = &lds[0];
  __syncthreads();
  const int b2 = m0 >> 11, h = n0 >> 6;
  if (g == 2) {
    // V: n-major [64][128] with granule-XOR; b128 readback along s
    #pragma unroll
    for (int mt = 0; mt < 4; ++mt)
      #pragma unroll
      for (int nt = 0; nt < 2; ++nt) {
        const int nl = wn + nt * 16 + fr;
        f32x4 r = acc[mt][nt];
        #pragma unroll
        for (int j = 0; j < 4; ++j) {
          const int sl = wm + mt * 16 + gh * 4 + j;
          eb[nl * 128 + (sl ^ ((nl & 7) << 4))] = f2bf(r[j] + bv[nt]);
        }
      }
    __syncthreads();
    #pragma unroll
    for (int it = 0; it < 4; ++it) {
      const int u = it * 256 + tid;
      const int nl = u >> 4, sc = u & 15;
      s16x8 v = *(const s16x8*)&eb[nl * 128 + ((sc * 8) ^ ((nl & 7) << 4))];
      *(s16x8*)&out[((size_t)((b2 * 16 + h) * 64 + nl)) * 2048 + (m0 & 2047) + sc * 8] = v;
    }
  } else {
    // Q/K: s-major [128][72] (8-aligned rows), b128 readback along d
    #pragma unroll
    for (int mt = 0; mt < 4; ++mt)
      #pragma unroll
      for (int nt = 0; nt < 2; ++nt) {
        const int nl = wn + nt * 16 + fr;
        f32x4 r = acc[mt][nt];
        #pragma unroll
        for (int j = 0; j < 4; ++j) {
          const int sl = wm + mt * 16 + gh * 4 + j;
          eb[sl * 72 + nl] = f2bf(r[j] + bv[nt]);
        }
      }
    __syncthreads();
    #pragma unroll
    for (int it = 0; it < 4; ++it) {
      const int u = it * 256 + tid;
      const int sl = u >> 3, c8 = (u & 7) * 8;
      s16x8 v = *(const s16x8*)&eb[sl * 72 + c8];
      *(s16x8*)&out[(((size_t)(b2 * 16 + h)) * 2048 + (m0 & 2047) + sl) * 64 + c8] = v;
    }
  }
}

// ---------- kernel 3b: O-proj bf16 GEMM, 128x64 tile, 4 waves, BK=64, dbuf ----------
__global__ __launch_bounds__(256, 3)
void gemm_oproj(const unsigned short* __restrict__ A, const unsigned short* __restrict__ B,
                const float* __restrict__ bias, float* __restrict__ out) {
  const int K = 1024, N = 1024;
  __shared__ __align__(16) unsigned short lds[24576];   // 48 KB
  const int tid = threadIdx.x;
  const int lane = tid & 63, wid = tid >> 6;

  const int nwg = 512;
  const int orig = blockIdx.x;
  const int swz = (orig & 7) * (nwg >> 3) + (orig >> 3);
  const int m0 = (swz >> 4) * 128, n0 = (swz & 15) * 64;

  const int wm = (wid >> 1) * 64, wn = (wid & 1) * 32;   // wave tile 64x32
  const int fr = lane & 15, gh = lane >> 4;

  const unsigned short* aP[4]; int aDst[4];
  #pragma unroll
  for (int s = 0; s < 4; ++s) {
    const int G = s * 256 + tid;
    const int r = G >> 3, slot = G & 7;
    const int gno = slot ^ (r & 7);
    const int ko = (gno >> 2) * 32 + (gno & 3) * 8;
    aP[s] = A + (size_t)(m0 + r) * K + ko;
    aDst[s] = G * 8;
  }
  const unsigned short* bP[2]; int bDst[2];
  #pragma unroll
  for (int s = 0; s < 2; ++s) {
    const int G = s * 256 + tid;
    const int r = G >> 3, slot = G & 7;
    const int gno = slot ^ (r & 7);
    const int ko = (gno >> 2) * 32 + (gno & 3) * 8;
    bP[s] = B + (size_t)(n0 + r) * K + ko;
    bDst[s] = G * 8;
  }
  auto stageAll = [&](int u, int kt) {
    #pragma unroll
    for (int s = 0; s < 4; ++s)
      gld_lds16(aP[s] + kt, &lds[u * 8192 + aDst[s]]);
    #pragma unroll
    for (int s = 0; s < 2; ++s)
      gld_lds16(bP[s] + kt, &lds[16384 + u * 4096 + bDst[s]]);
  };

  f32x4 acc[4][2] = {};

  stageAll(0, 0);
  asm volatile("s_waitcnt vmcnt(0)" ::: "memory");
  __builtin_amdgcn_s_barrier();
  __builtin_amdgcn_sched_barrier(0);

  #pragma unroll 1
  for (int t = 0; t < 16; ++t) {
    const int u = t & 1;
    if (t < 15) stageAll(u ^ 1, (t + 1) * 64);
    const unsigned short* La = &lds[u * 8192];
    const unsigned short* Lb = &lds[16384 + u * 4096];
    s16x8 b[2][2];
    #pragma unroll
    for (int ks = 0; ks < 2; ++ks)
      #pragma unroll
      for (int nt = 0; nt < 2; ++nt) {
        const int br = wn + nt * 16 + fr;
        b[ks][nt] = *(const s16x8*)&Lb[br * 64 + (((ks << 2) | gh) ^ (br & 7)) * 8];
      }
    #pragma unroll
    for (int q = 0; q < 2; ++q) {
      s16x8 a[2][2];
      #pragma unroll
      for (int i = 0; i < 2; ++i)
        #pragma unroll
        for (int ks = 0; ks < 2; ++ks) {
          const int ar = wm + (q * 2 + i) * 16 + fr;
          a[i][ks] = *(const s16x8*)&La[ar * 64 + (((ks << 2) | gh) ^ (ar & 7)) * 8];
        }
      #pragma unroll
      for (int i = 0; i < 2; ++i)
        #pragma unroll
        for (int nt = 0; nt < 2; ++nt) {
          acc[q * 2 + i][nt] = MFMA16(a[i][0], b[0][nt], acc[q * 2 + i][nt]);
          acc[q * 2 + i][nt] = MFMA16(a[i][1], b[1][nt], acc[q * 2 + i][nt]);
        }
    }
    __builtin_amdgcn_sched_barrier(0);
    if (t < 15) { asm volatile("s_waitcnt vmcnt(0)" ::: "memory"); }
    __builtin_amdgcn_s_barrier();
    __builtin_amdgcn_sched_barrier(0);
  }

  #pragma unroll
  for (int mt = 0; mt < 4; ++mt) {
    const int gm = m0 + wm + mt * 16 + (gh << 2);
    #pragma unroll
    for (int nt = 0; nt < 2; ++nt) {
      const int gn = n0 + wn + nt * 16 + fr;
      const float bvv = bias[gn];
      f32x4 r = acc[mt][nt];
      #pragma unroll
      for (int j = 0; j < 4; ++j)
        out[(size_t)(gm + j) * N + gn] = r[j] + bvv;
    }
  }
}

// ---------- kernel 4: block-diagonal attention, MFMA core ----------
__global__ __launch_bounds__(256, 4)
void attn_mfma(const unsigned short* __restrict__ Q, const unsigned short* __restrict__ Kb,
               const unsigned short* __restrict__ Vt, unsigned short* __restrict__ X) {
  __shared__ __align__(16) unsigned short qs[4096];
  __shared__ __align__(16) unsigned short ks2[4096];
  __shared__ __align__(16) unsigned short vs[4096];
  __shared__ __align__(16) unsigned short ps[4096];
  const int tid = threadIdx.x, lane = tid & 63, w = tid >> 6;
  const int hb = blockIdx.x >> 5, qb = blockIdx.x & 31;
  const size_t qkbase = ((size_t)hb * 2048 + qb * 64) * 64;
  const size_t vbase = (size_t)hb * 64 * 2048 + qb * 64;

  #pragma unroll
  for (int i = 0; i < 2; ++i) {
    const int G = i * 256 + tid;
    const int row = G >> 3, slot = G & 7;
    const int sg = slot ^ (row & 7);
    gld_lds16(Q + qkbase + row * 64 + sg * 8, &qs[G * 8]);
    gld_lds16(Kb + qkbase + row * 64 + sg * 8, &ks2[G * 8]);
  }
  #pragma unroll
  for (int i = 0; i < 2; ++i) {
    const int G = i * 256 + tid;
    const int row = G >> 3, slot = G & 7;
    const int sg = slot ^ (row & 7);
    gld_lds16(Vt + vbase + (size_t)row * 2048 + sg * 8, &vs[G * 8]);
  }
  asm volatile("s_waitcnt vmcnt(2)" ::: "memory");   // Q,K retired; V in flight
  __builtin_amdgcn_s_barrier();
  __builtin_amdgcn_sched_barrier(0);

  const int fr = lane & 15, gh = lane >> 4;
  const int arow = w * 16 + fr;

  s16x8 aq[2], bk[2][4];
  #pragma unroll
  for (int ks = 0; ks < 2; ++ks) {
    aq[ks] = *(const s16x8*)&qs[arow * 64 + (((ks * 4 + gh) ^ (arow & 7)) << 3)];
    #pragma unroll
    for (int nt = 0; nt < 4; ++nt) {
      const int krow = nt * 16 + fr;
      bk[ks][nt] = *(const s16x8*)&ks2[krow * 64 + (((ks * 4 + gh) ^ (krow & 7)) << 3)];
    }
  }
  f32x4 s[4] = {};
  #pragma unroll
  for (int ks = 0; ks < 2; ++ks)
    #pragma unroll
    for (int nt = 0; nt < 4; ++nt)
      s[nt] = MFMA16(aq[ks], bk[ks][nt], s[nt]);

  #pragma unroll
  for (int j = 0; j < 4; ++j) {
    float t0 = s[0][j] * 0.125f, t1 = s[1][j] * 0.125f;
    float t2 = s[2][j] * 0.125f, t3 = s[3][j] * 0.125f;
    float m = fmaxf(fmaxf(t0, t1), fmaxf(t2, t3));
    m = fmaxf(m, __shfl_xor(m, 1, 64));
    m = fmaxf(m, __shfl_xor(m, 2, 64));
    m = fmaxf(m, __shfl_xor(m, 4, 64));
    m = fmaxf(m, __shfl_xor(m, 8, 64));
    t0 = __expf(t0 - m); t1 = __expf(t1 - m);
    t2 = __expf(t2 - m); t3 = __expf(t3 - m);
    float sum = t0 + t1 + t2 + t3;
    sum += __shfl_xor(sum, 1, 64);
    sum += __shfl_xor(sum, 2, 64);
    sum += __shfl_xor(sum, 4, 64);
    sum += __shfl_xor(sum, 8, 64);
    const float r = 1.0f / sum;
    s[0][j] = t0 * r; s[1][j] = t1 * r; s[2][j] = t2 * r; s[3][j] = t3 * r;
  }

  #pragma unroll
  for (int j = 0; j < 4; ++j) {
    const int q = w * 16 + gh * 4 + j;
    #pragma unroll
    for (int nt = 0; nt < 4; ++nt) {
      const int k = nt * 16 + fr;
      ps[q * 64 + (((k >> 3) ^ (q & 7)) << 3) + (k & 7)] = f2bf(s[nt][j]);
    }
  }

  asm volatile("s_waitcnt vmcnt(0)" ::: "memory");
  __builtin_amdgcn_s_barrier();
  __builtin_amdgcn_sched_barrier(0);

  s16x8 ap[2], bv2[2][4];
  #pragma unroll
  for (int ks = 0; ks < 2; ++ks) {
    ap[ks] = *(const s16x8*)&ps[arow * 64 + (((ks * 4 + gh) ^ (arow & 7)) << 3)];
    #pragma unroll
    for (int nt = 0; nt < 4; ++nt) {
      const int drow = nt * 16 + fr;
      bv2[ks][nt] = *(const s16x8*)&vs[drow * 64 + (((ks * 4 + gh) ^ (drow & 7)) << 3)];
    }
  }
  f32x4 x[4] = {};
  #pragma unroll
  for (int ks = 0; ks < 2; ++ks)
    #pragma unroll
    for (int nt = 0; nt < 4; ++nt)
      x[nt] = MFMA16(ap[ks], bv2[ks][nt], x[nt]);

  const int b = hb >> 4, h = hb & 15;
  #pragma unroll
  for (int nt = 0; nt < 4; ++nt)
    #pragma unroll
    for (int j = 0; j < 4; ++j) {
      const int sgl = qb * 64 + w * 16 + gh * 4 + j;
      X[((size_t)(b * 2048 + sgl)) * 1024 + h * 64 + nt * 16 + fr] = f2bf(x[nt][j]);
    }
}

// ---------- launch ----------
extern "C" void kernel_launch(void* const* d_in, const int* in_sizes, int n_in,
                              void* d_out, int out_size, void* d_ws, size_t ws_size,
                              hipStream_t stream) {
  const float* query = (const float*)d_in[0];
  const float* key   = (const float*)d_in[1];
  const float* value = (const float*)d_in[2];
  const float* Wq = (const float*)d_in[3]; const float* bq = (const float*)d_in[4];
  const float* Wk = (const float*)d_in[5]; const float* bk = (const float*)d_in[6];
  const float* Wv = (const float*)d_in[7]; const float* bv = (const float*)d_in[8];
  const float* Wo = (const float*)d_in[9]; const float* bo = (const float*)d_in[10];
  float* out = (float*)d_out;

  const size_t W_E = 1024 * 1024;
  const size_t X_E = 4096 * 1024;
  unsigned char* p = (unsigned char*)d_ws;
  auto take = [&](size_t bytes) { void* r = (void*)p; p += bytes; return r; };

  unsigned short* wtq = (unsigned short*)take(W_E * 2);
  unsigned short* wtk = (unsigned short*)take(W_E * 2);
  unsigned short* wtv = (unsigned short*)take(W_E * 2);
  unsigned short* wto = (unsigned short*)take(W_E * 2);
  unsigned short* xq = (unsigned short*)take(X_E * 2);
  unsigned short* xk = (unsigned short*)take(X_E * 2);
  unsigned short* xv = (unsigned short*)take(X_E * 2);
  unsigned short* Qb = (unsigned short*)take(X_E * 2);
  unsigned short* Kb = (unsigned short*)take(X_E * 2);
  unsigned short* Vt = (unsigned short*)take(X_E * 2);
  unsigned short* ao = (unsigned short*)take(X_E * 2);
  (void)ws_size; (void)in_sizes; (void)n_in; (void)out_size;

  prep<<<dim3(13312), 256, 0, stream>>>(query, xq, key, xk, value, xv,
                                        Wq, wtq, Wk, wtk, Wv, wtv, Wo, wto);

  QkvArgs qkv = {};
  qkv.A[0] = xq; qkv.B[0] = wtq; qkv.bias[0] = bq; qkv.out[0] = Qb;
  qkv.A[1] = xk; qkv.B[1] = wtk; qkv.bias[1] = bk; qkv.out[1] = Kb;
  qkv.A[2] = xv; qkv.B[2] = wtv; qkv.bias[2] = bv; qkv.out[2] = Vt;
  gemm_qkv<<<dim3(1536), 256, 0, stream>>>(qkv);

  attn_mfma<<<dim3(1024), 256, 0, stream>>>(Qb, Kb, Vt, ao);

  gemm_oproj<<<dim3(512), 256, 0, stream>>>(ao, wto, bo, out);
}

// Round 16
// 75.056 us; speedup vs baseline: 1.0124x; 1.0124x over previous
//
#include <hip/hip_runtime.h>
#include <hip/hip_bf16.h>

// ---------- helpers ----------
typedef __attribute__((ext_vector_type(4))) float f32x4;
typedef __attribute__((ext_vector_type(8))) short s16x8;

#define MFMA16(a, b, c) __builtin_amdgcn_mfma_f32_16x16x32_bf16(a, b, c, 0, 0, 0)

__device__ __forceinline__ void gld_lds16(const void* g, void* l) {
  __builtin_amdgcn_global_load_lds(
      (const __attribute__((address_space(1))) unsigned int*)g,
      (__attribute__((address_space(3))) unsigned int*)l, 16, 0, 0);
}

__device__ __forceinline__ unsigned short f2bf(float f) {
  union { __hip_bfloat16 b; unsigned short u; } cv;
  cv.b = __float2bfloat16(f);
  return cv.u;
}
__device__ __forceinline__ float bf2f(unsigned short u) {
  union { unsigned short u; __hip_bfloat16 b; } cv;
  cv.u = u;
  return __bfloat162float(cv.b);
}

// ---------- kernel 1: merged prepass ----------
__global__ void prep(const float* Xq, unsigned short* xq,
                     const float* Xk, unsigned short* xk,
                     const float* Xv, unsigned short* xv,
                     const float* W0, unsigned short* H0,
                     const float* W1, unsigned short* H1,
                     const float* W2, unsigned short* H2,
                     const float* W3, unsigned short* H3) {
  __shared__ float tile[64 * 65];
  const int bid = blockIdx.x;
  const int t = threadIdx.x;
  if (bid < 12288) {
    const float* src; unsigned short* h;
    const int which = bid / 4096;
    if (which == 0) { src = Xq; h = xq; }
    else if (which == 1) { src = Xk; h = xk; }
    else { src = Xv; h = xv; }
    const int i = (bid - which * 4096) * 256 + t;   // float4 unit
    float4 v = ((const float4*)src)[i];
    ((ushort4*)h)[i] = make_ushort4(f2bf(v.x), f2bf(v.y), f2bf(v.z), f2bf(v.w));
  } else {
    const int bid2 = bid - 12288;
    const float* W; unsigned short* H;
    switch (bid2 >> 8) {
      case 0: W = W0; H = H0; break;
      case 1: W = W1; H = H1; break;
      case 2: W = W2; H = H2; break;
      default: W = W3; H = H3; break;
    }
    const int tx = bid2 & 255;
    const int tk0 = (tx & 15) * 64;   // k tile
    const int tn0 = (tx >> 4) * 64;   // n tile
    for (int i = 0; i < 16; ++i) {
      int idx = i * 256 + t;
      int r = idx >> 6, c = idx & 63;
      tile[r * 65 + c] = W[(size_t)(tk0 + r) * 1024 + tn0 + c];
    }
    __syncthreads();
    for (int i = 0; i < 16; ++i) {
      int idx = i * 256 + t;
      int r = idx >> 6, c = idx & 63;   // r: n offset, c: k offset
      H[(size_t)(tn0 + r) * 1024 + tk0 + c] = f2bf(tile[c * 65 + r]);
    }
  }
}

// ---------- LDS layout (BK=64, bf16) ----------
// Row = 64 shorts = one 128-B LDS row. Granule gno of row r at slot
// gno^(r&7); gno -> k offset (gno>>2)*32 + (gno&3)*8.
// Read frag (row ar, k-group ks, lane gh): slot = ((ks<<2)|gh) ^ (ar&7).

// ---------- kernel 3a: QKV bf16 GEMM, 256x256 tile, 8 waves, BK=64, dbuf ----------
// Session-best schedule (R10/R14): stage-all(t+1) at step top; one vmcnt(0)+
// barrier per step. Epilogue via LDS transpose; V stored n-major w/ XOR.
// g==0,1 (Q,K): out [b*16+h][s][64]. g==2 (V): out TRANSPOSED [b*16+h][d][2048 s].
struct QkvArgs {
  const unsigned short* A[3];
  const unsigned short* B[3];
  const float* bias[3];
  unsigned short* out[3];
};

__global__ __launch_bounds__(512, 2)
void gemm_qkv(QkvArgs args) {
  const int K = 1024;
  __shared__ __align__(16) unsigned short lds[65536];   // 128 KB
  const int tid = threadIdx.x;
  const int lane = tid & 63, w = tid >> 6;

  // XCD-aware bijective swizzle (192 % 8 == 0)
  const int nwg = 192;
  const int orig = blockIdx.x;
  const int swz = (orig & 7) * (nwg >> 3) + (orig >> 3);
  const int g = swz >> 6;          // 64 blocks per gemm (16 M x 4 N)
  const int tl = swz & 63;
  const int m0 = (tl >> 2) * 256, n0 = (tl & 3) * 256;

  const unsigned short* A = args.A[g];
  const unsigned short* B = args.B[g];
  const float* bias = args.bias[g];
  unsigned short* out = args.out[g];

  const int wm = (w >> 2) * 128, wn = (w & 3) * 64;   // wave tile 128x64
  const int fr = lane & 15, gh = lane >> 4;

  // staging sources: 4 sweeps per matrix per K-tile (8 gld/thread/step)
  const unsigned short* aP[4]; const unsigned short* bP[4]; int dstoff[4];
  #pragma unroll
  for (int s = 0; s < 4; ++s) {
    const int G = s * 512 + tid;
    const int r = G >> 3, slot = G & 7;
    const int gno = slot ^ (r & 7);
    const int ko = (gno >> 2) * 32 + (gno & 3) * 8;
    aP[s] = A + (size_t)(m0 + r) * K + ko;
    bP[s] = B + (size_t)(n0 + r) * K + ko;
    dstoff[s] = G * 8;
  }
  auto stageAll = [&](int u, int kt) {
    #pragma unroll
    for (int s = 0; s < 4; ++s) {
      gld_lds16(aP[s] + kt, &lds[u * 16384 + dstoff[s]]);
      gld_lds16(bP[s] + kt, &lds[32768 + u * 16384 + dstoff[s]]);
    }
  };

  f32x4 acc[8][4] = {};

  // prologue: stage K-tile 0 into buf 0
  stageAll(0, 0);
  asm volatile("s_waitcnt vmcnt(0)" ::: "memory");
  __builtin_amdgcn_s_barrier();
  __builtin_amdgcn_sched_barrier(0);

  #pragma unroll 1
  for (int t = 0; t < 16; ++t) {
    const int u = t & 1;
    if (t < 15) stageAll(u ^ 1, (t + 1) * 64);   // issue early: full step in flight
    const unsigned short* La = &lds[u * 16384];
    const unsigned short* Lb = &lds[32768 + u * 16384];
    s16x8 b[2][4];
    #pragma unroll
    for (int ks = 0; ks < 2; ++ks)
      #pragma unroll
      for (int nt = 0; nt < 4; ++nt) {
        const int br = wn + nt * 16 + fr;
        b[ks][nt] = *(const s16x8*)&Lb[br * 64 + (((ks << 2) | gh) ^ (br & 7)) * 8];
      }
    #pragma unroll
    for (int q = 0; q < 4; ++q) {
      s16x8 a[2][2];
      #pragma unroll
      for (int i = 0; i < 2; ++i)
        #pragma unroll
        for (int ks = 0; ks < 2; ++ks) {
          const int ar = wm + (q * 2 + i) * 16 + fr;
          a[i][ks] = *(const s16x8*)&La[ar * 64 + (((ks << 2) | gh) ^ (ar & 7)) * 8];
        }
      #pragma unroll
      for (int i = 0; i < 2; ++i)
        #pragma unroll
        for (int nt = 0; nt < 4; ++nt) {
          acc[q * 2 + i][nt] = MFMA16(a[i][0], b[0][nt], acc[q * 2 + i][nt]);
          acc[q * 2 + i][nt] = MFMA16(a[i][1], b[1][nt], acc[q * 2 + i][nt]);
        }
    }
    __builtin_amdgcn_sched_barrier(0);
    if (t < 15) { asm volatile("s_waitcnt vmcnt(0)" ::: "memory"); }
    __builtin_amdgcn_s_barrier();
    __builtin_amdgcn_sched_barrier(0);
  }

  // ---- epilogue: acc -> LDS (256x256 bf16, 128 KB) -> coalesced 16B stores
  float bv[4];
  #pragma unroll
  for (int nt = 0; nt < 4; ++nt) bv[nt] = bias[n0 + wn + nt * 16 + fr];
  unsigned short* eb = &lds[0];   // 65536 shorts = 256 x 256
  __syncthreads();
  if (g == 2) {
    // V: store C^T n-major with per-row XOR; s-major re-read is b128 conflict-free
    #pragma unroll
    for (int mt = 0; mt < 8; ++mt)
      #pragma unroll
      for (int nt = 0; nt < 4; ++nt) {
        const int nl = wn + nt * 16 + fr;
        f32x4 r = acc[mt][nt];
        #pragma unroll
        for (int j = 0; j < 4; ++j) {
          const int sl = wm + mt * 16 + gh * 4 + j;
          eb[nl * 256 + (sl ^ ((nl & 7) << 3))] = f2bf(r[j] + bv[nt]);
        }
      }
  } else {
    #pragma unroll
    for (int mt = 0; mt < 8; ++mt)
      #pragma unroll
      for (int nt = 0; nt < 4; ++nt) {
        const int nl = wn + nt * 16 + fr;
        f32x4 r = acc[mt][nt];
        #pragma unroll
        for (int j = 0; j < 4; ++j) {
          const int sl = wm + mt * 16 + gh * 4 + j;
          eb[sl * 256 + nl] = f2bf(r[j] + bv[nt]);
        }
      }
  }
  __syncthreads();
  const int b2 = m0 >> 11;
  if (g == 2) {
    // out[b*16+h][d][2048 s]: thread copies 8 shorts along s (b128 LDS read)
    #pragma unroll
    for (int it = 0; it < 16; ++it) {
      const int u = it * 512 + tid;
      const int nl = u >> 5, sc = u & 31;
      s16x8 v = *(const s16x8*)&eb[nl * 256 + ((sc * 8) ^ ((nl & 7) << 3))];
      const int gn = n0 + nl, h = gn >> 6, d = gn & 63;
      *(s16x8*)&out[((size_t)((b2 * 16 + h) * 64 + d)) * 2048 + (m0 & 2047) + sc * 8] = v;
    }
  } else {
    // out[b*16+h][s][64]: thread copies 8 shorts along d (16B store)
    #pragma unroll
    for (int it = 0; it < 16; ++it) {
      const int u = it * 512 + tid;
      const int sl = u >> 5, n8 = (u & 31) * 8;
      s16x8 v = *(const s16x8*)&eb[sl * 256 + n8];
      const int s = m0 + sl;
      const int gn = n0 + n8, h = gn >> 6, d = gn & 63;
      *(s16x8*)&out[(((size_t)(b2 * 16 + h)) * 2048 + (s & 2047)) * 64 + d] = v;
    }
  }
}

// ---------- kernel 3b: O-proj bf16 GEMM, 128x64 tile, 4 waves, BK=64, dbuf ----------
// 512 blocks, 48 KB LDS -> ~2-3 blocks/CU resident (best measured GEMM rate).
__global__ __launch_bounds__(256, 3)
void gemm_oproj(const unsigned short* __restrict__ A, const unsigned short* __restrict__ B,
                const float* __restrict__ bias, float* __restrict__ out) {
  const int K = 1024, N = 1024;
  __shared__ __align__(16) unsigned short lds[24576];   // A 2x16KB | B 2x8KB = 48 KB
  const int tid = threadIdx.x;
  const int lane = tid & 63, wid = tid >> 6;

  // XCD-aware bijective swizzle (512 % 8 == 0)
  const int nwg = 512;
  const int orig = blockIdx.x;
  const int swz = (orig & 7) * (nwg >> 3) + (orig >> 3);
  const int m0 = (swz >> 4) * 128, n0 = (swz & 15) * 64;

  const int wm = (wid >> 1) * 64, wn = (wid & 1) * 32;   // wave tile 64x32
  const int fr = lane & 15, gh = lane >> 4;

  // A: 128 rows -> 4 sweeps; B: 64 rows -> 2 sweeps
  const unsigned short* aP[4]; int aDst[4];
  #pragma unroll
  for (int s = 0; s < 4; ++s) {
    const int G = s * 256 + tid;
    const int r = G >> 3, slot = G & 7;
    const int gno = slot ^ (r & 7);
    const int ko = (gno >> 2) * 32 + (gno & 3) * 8;
    aP[s] = A + (size_t)(m0 + r) * K + ko;
    aDst[s] = G * 8;
  }
  const unsigned short* bP[2]; int bDst[2];
  #pragma unroll
  for (int s = 0; s < 2; ++s) {
    const int G = s * 256 + tid;
    const int r = G >> 3, slot = G & 7;
    const int gno = slot ^ (r & 7);
    const int ko = (gno >> 2) * 32 + (gno & 3) * 8;
    bP[s] = B + (size_t)(n0 + r) * K + ko;
    bDst[s] = G * 8;
  }
  auto stageAll = [&](int u, int kt) {
    #pragma unroll
    for (int s = 0; s < 4; ++s)
      gld_lds16(aP[s] + kt, &lds[u * 8192 + aDst[s]]);
    #pragma unroll
    for (int s = 0; s < 2; ++s)
      gld_lds16(bP[s] + kt, &lds[16384 + u * 4096 + bDst[s]]);
  };

  f32x4 acc[4][2] = {};

  stageAll(0, 0);
  asm volatile("s_waitcnt vmcnt(0)" ::: "memory");
  __builtin_amdgcn_s_barrier();
  __builtin_amdgcn_sched_barrier(0);

  #pragma unroll 1
  for (int t = 0; t < 16; ++t) {
    const int u = t & 1;
    if (t < 15) stageAll(u ^ 1, (t + 1) * 64);
    const unsigned short* La = &lds[u * 8192];
    const unsigned short* Lb = &lds[16384 + u * 4096];
    s16x8 b[2][2];
    #pragma unroll
    for (int ks = 0; ks < 2; ++ks)
      #pragma unroll
      for (int nt = 0; nt < 2; ++nt) {
        const int br = wn + nt * 16 + fr;
        b[ks][nt] = *(const s16x8*)&Lb[br * 64 + (((ks << 2) | gh) ^ (br & 7)) * 8];
      }
    #pragma unroll
    for (int q = 0; q < 2; ++q) {
      s16x8 a[2][2];
      #pragma unroll
      for (int i = 0; i < 2; ++i)
        #pragma unroll
        for (int ks = 0; ks < 2; ++ks) {
          const int ar = wm + (q * 2 + i) * 16 + fr;
          a[i][ks] = *(const s16x8*)&La[ar * 64 + (((ks << 2) | gh) ^ (ar & 7)) * 8];
        }
      #pragma unroll
      for (int i = 0; i < 2; ++i)
        #pragma unroll
        for (int nt = 0; nt < 2; ++nt) {
          acc[q * 2 + i][nt] = MFMA16(a[i][0], b[0][nt], acc[q * 2 + i][nt]);
          acc[q * 2 + i][nt] = MFMA16(a[i][1], b[1][nt], acc[q * 2 + i][nt]);
        }
    }
    __builtin_amdgcn_sched_barrier(0);
    if (t < 15) { asm volatile("s_waitcnt vmcnt(0)" ::: "memory"); }
    __builtin_amdgcn_s_barrier();
    __builtin_amdgcn_sched_barrier(0);
  }

  #pragma unroll
  for (int mt = 0; mt < 4; ++mt) {
    const int gm = m0 + wm + mt * 16 + (gh << 2);
    #pragma unroll
    for (int nt = 0; nt < 2; ++nt) {
      const int gn = n0 + wn + nt * 16 + fr;
      const float bvv = bias[gn];
      f32x4 r = acc[mt][nt];
      #pragma unroll
      for (int j = 0; j < 4; ++j)
        out[(size_t)(gm + j) * N + gn] = r[j] + bvv;
    }
  }
}

// ---------- kernel 4: block-diagonal attention, MFMA core ----------
// grid 1024 = hb*32 + qb. Q,K: [hb][2048 s][64 d] bf16. Vt: [hb][64 d][2048 s] bf16.
// 32 KB LDS, __launch_bounds__(256,4): 4 co-resident blocks/CU hide fetch latency.
__global__ __launch_bounds__(256, 4)
void attn_mfma(const unsigned short* __restrict__ Q, const unsigned short* __restrict__ Kb,
               const unsigned short* __restrict__ Vt, unsigned short* __restrict__ X) {
  __shared__ __align__(16) unsigned short qs[4096];
  __shared__ __align__(16) unsigned short ks2[4096];
  __shared__ __align__(16) unsigned short vs[4096];
  __shared__ __align__(16) unsigned short ps[4096];
  const int tid = threadIdx.x, lane = tid & 63, w = tid >> 6;
  const int hb = blockIdx.x >> 5, qb = blockIdx.x & 31;
  const size_t qkbase = ((size_t)hb * 2048 + qb * 64) * 64;
  const size_t vbase = (size_t)hb * 64 * 2048 + qb * 64;

  // stage Q,K first, then V (issue order = retirement order for vmcnt)
  #pragma unroll
  for (int i = 0; i < 2; ++i) {
    const int G = i * 256 + tid;
    const int row = G >> 3, slot = G & 7;
    const int sg = slot ^ (row & 7);
    gld_lds16(Q + qkbase + row * 64 + sg * 8, &qs[G * 8]);
    gld_lds16(Kb + qkbase + row * 64 + sg * 8, &ks2[G * 8]);
  }
  #pragma unroll
  for (int i = 0; i < 2; ++i) {
    const int G = i * 256 + tid;
    const int row = G >> 3, slot = G & 7;
    const int sg = slot ^ (row & 7);
    gld_lds16(Vt + vbase + (size_t)row * 2048 + sg * 8, &vs[G * 8]);
  }
  asm volatile("s_waitcnt vmcnt(2)" ::: "memory");   // Q,K retired; V in flight
  __builtin_amdgcn_s_barrier();
  __builtin_amdgcn_sched_barrier(0);

  const int fr = lane & 15, gh = lane >> 4;
  const int arow = w * 16 + fr;   // this wave's A rows (q)

  // ---- QK^T: S[16q][64k] per wave
  s16x8 aq[2], bk[2][4];
  #pragma unroll
  for (int ks = 0; ks < 2; ++ks) {
    aq[ks] = *(const s16x8*)&qs[arow * 64 + (((ks * 4 + gh) ^ (arow & 7)) << 3)];
    #pragma unroll
    for (int nt = 0; nt < 4; ++nt) {
      const int krow = nt * 16 + fr;
      bk[ks][nt] = *(const s16x8*)&ks2[krow * 64 + (((ks * 4 + gh) ^ (krow & 7)) << 3)];
    }
  }
  f32x4 s[4] = {};
  #pragma unroll
  for (int ks = 0; ks < 2; ++ks)
    #pragma unroll
    for (int nt = 0; nt < 4; ++nt)
      s[nt] = MFMA16(aq[ks], bk[ks][nt], s[nt]);

  // ---- softmax: D row q = gh*4+j, col k = nt*16+fr -> reduce over fr's 16 lanes
  #pragma unroll
  for (int j = 0; j < 4; ++j) {
    float t0 = s[0][j] * 0.125f, t1 = s[1][j] * 0.125f;
    float t2 = s[2][j] * 0.125f, t3 = s[3][j] * 0.125f;
    float m = fmaxf(fmaxf(t0, t1), fmaxf(t2, t3));
    m = fmaxf(m, __shfl_xor(m, 1, 64));
    m = fmaxf(m, __shfl_xor(m, 2, 64));
    m = fmaxf(m, __shfl_xor(m, 4, 64));
    m = fmaxf(m, __shfl_xor(m, 8, 64));
    t0 = __expf(t0 - m); t1 = __expf(t1 - m);
    t2 = __expf(t2 - m); t3 = __expf(t3 - m);
    float sum = t0 + t1 + t2 + t3;
    sum += __shfl_xor(sum, 1, 64);
    sum += __shfl_xor(sum, 2, 64);
    sum += __shfl_xor(sum, 4, 64);
    sum += __shfl_xor(sum, 8, 64);
    const float r = 1.0f / sum;
    s[0][j] = t0 * r; s[1][j] = t1 * r; s[2][j] = t2 * r; s[3][j] = t3 * r;
  }

  // ---- P -> bf16 LDS (swizzled); wave writes/reads only its own 16 rows
  #pragma unroll
  for (int j = 0; j < 4; ++j) {
    const int q = w * 16 + gh * 4 + j;
    #pragma unroll
    for (int nt = 0; nt < 4; ++nt) {
      const int k = nt * 16 + fr;
      ps[q * 64 + (((k >> 3) ^ (q & 7)) << 3) + (k & 7)] = f2bf(s[nt][j]);
    }
  }

  // ---- drain V, sync, then PV
  asm volatile("s_waitcnt vmcnt(0)" ::: "memory");
  __builtin_amdgcn_s_barrier();
  __builtin_amdgcn_sched_barrier(0);

  s16x8 ap[2], bv2[2][4];
  #pragma unroll
  for (int ks = 0; ks < 2; ++ks) {
    ap[ks] = *(const s16x8*)&ps[arow * 64 + (((ks * 4 + gh) ^ (arow & 7)) << 3)];
    #pragma unroll
    for (int nt = 0; nt < 4; ++nt) {
      const int drow = nt * 16 + fr;
      bv2[ks][nt] = *(const s16x8*)&vs[drow * 64 + (((ks * 4 + gh) ^ (drow & 7)) << 3)];
    }
  }
  f32x4 x[4] = {};
  #pragma unroll
  for (int ks = 0; ks < 2; ++ks)
    #pragma unroll
    for (int nt = 0; nt < 4; ++nt)
      x[nt] = MFMA16(ap[ks], bv2[ks][nt], x[nt]);

  // ---- write X: [b*2048 + s][h*64 + d] bf16
  const int b = hb >> 4, h = hb & 15;
  #pragma unroll
  for (int nt = 0; nt < 4; ++nt)
    #pragma unroll
    for (int j = 0; j < 4; ++j) {
      const int sgl = qb * 64 + w * 16 + gh * 4 + j;
      X[((size_t)(b * 2048 + sgl)) * 1024 + h * 64 + nt * 16 + fr] = f2bf(x[nt][j]);
    }
}

// ---------- launch ----------
extern "C" void kernel_launch(void* const* d_in, const int* in_sizes, int n_in,
                              void* d_out, int out_size, void* d_ws, size_t ws_size,
                              hipStream_t stream) {
  const float* query = (const float*)d_in[0];
  const float* key   = (const float*)d_in[1];
  const float* value = (const float*)d_in[2];
  const float* Wq = (const float*)d_in[3]; const float* bq = (const float*)d_in[4];
  const float* Wk = (const float*)d_in[5]; const float* bk = (const float*)d_in[6];
  const float* Wv = (const float*)d_in[7]; const float* bv = (const float*)d_in[8];
  const float* Wo = (const float*)d_in[9]; const float* bo = (const float*)d_in[10];
  float* out = (float*)d_out;

  const size_t W_E = 1024 * 1024;
  const size_t X_E = 4096 * 1024;
  unsigned char* p = (unsigned char*)d_ws;
  auto take = [&](size_t bytes) { void* r = (void*)p; p += bytes; return r; };

  unsigned short* wtq = (unsigned short*)take(W_E * 2);
  unsigned short* wtk = (unsigned short*)take(W_E * 2);
  unsigned short* wtv = (unsigned short*)take(W_E * 2);
  unsigned short* wto = (unsigned short*)take(W_E * 2);
  unsigned short* xq = (unsigned short*)take(X_E * 2);
  unsigned short* xk = (unsigned short*)take(X_E * 2);
  unsigned short* xv = (unsigned short*)take(X_E * 2);
  unsigned short* Qb = (unsigned short*)take(X_E * 2);
  unsigned short* Kb = (unsigned short*)take(X_E * 2);
  unsigned short* Vt = (unsigned short*)take(X_E * 2);
  unsigned short* ao = (unsigned short*)take(X_E * 2);
  (void)ws_size; (void)in_sizes; (void)n_in; (void)out_size;

  // merged convert + transpose prepass
  prep<<<dim3(13312), 256, 0, stream>>>(query, xq, key, xk, value, xv,
                                        Wq, wtq, Wk, wtk, Wv, wtv, Wo, wto);

  QkvArgs qkv = {};
  qkv.A[0] = xq; qkv.B[0] = wtq; qkv.bias[0] = bq; qkv.out[0] = Qb;
  qkv.A[1] = xk; qkv.B[1] = wtk; qkv.bias[1] = bk; qkv.out[1] = Kb;
  qkv.A[2] = xv; qkv.B[2] = wtv; qkv.bias[2] = bv; qkv.out[2] = Vt;
  gemm_qkv<<<dim3(192), 512, 0, stream>>>(qkv);

  attn_mfma<<<dim3(1024), 256, 0, stream>>>(Qb, Kb, Vt, ao);

  gemm_oproj<<<dim3(512), 256, 0, stream>>>(ao, wto, bo, out);
}